// Round 1
// baseline (89.441 us; speedup 1.0000x reference)
//
#include <hip/hip_runtime.h>
#include <math.h>

#define NG 2048
#define FEATN 128
#define NPIX 16384
#define NCHUNK 8
#define CHSZ 256

// ws layout (float offsets)
// raw params: 10 arrays of NG  : u,v,cA,cB,cC,op,r,g,b,tz
#define RAW_OFF 0
// sorted params: 9 arrays of NG: u,v,cA,cB,cC,op,r,g,b
#define SORT_OFF (10 * NG)           // 20480
// per-chunk transmittance: NCHUNK * NPIX
#define CT_OFF (SORT_OFF + 9 * NG)   // 38912
// per-chunk accum rgb: NCHUNK * 3 * NPIX
#define CA_OFF (CT_OFF + NCHUNK * NPIX)  // 169984

__device__ __forceinline__ float sigmoidf_(float z) { return 1.0f / (1.0f + expf(-z)); }

__global__ __launch_bounds__(256) void k_pre(
    const float* __restrict__ x, const float* __restrict__ pts, const float* __restrict__ vm,
    const float* __restrict__ w_shs, const float* __restrict__ b_shs,
    const float* __restrict__ w_scale, const float* __restrict__ b_scale,
    const float* __restrict__ w_xyz, const float* __restrict__ b_xyz,
    const float* __restrict__ w_opac, const float* __restrict__ b_opac,
    const float* __restrict__ w_rot, const float* __restrict__ b_rot,
    float* __restrict__ ws)
{
    __shared__ float sw[14 * FEATN];
    int tid = threadIdx.x;
    for (int i = tid; i < 14 * FEATN; i += 256) {
        int r = i >> 7, c0 = i & 127;
        float v;
        if (r < 3)       v = w_shs[r * FEATN + c0];
        else if (r < 6)  v = w_scale[(r - 3) * FEATN + c0];
        else if (r < 9)  v = w_xyz[(r - 6) * FEATN + c0];
        else if (r == 9) v = w_opac[c0];
        else             v = w_rot[(r - 10) * FEATN + c0];
        sw[i] = v;
    }
    __syncthreads();
    int g = blockIdx.x * 256 + tid;

    float acc[14];
#pragma unroll
    for (int j = 0; j < 14; j++) acc[j] = 0.0f;
    const float4* x4 = (const float4*)(x + (size_t)g * FEATN);
    for (int k4 = 0; k4 < FEATN / 4; k4++) {
        float4 xv = x4[k4];
#pragma unroll
        for (int j = 0; j < 14; j++) {
            const float* wr = &sw[j * FEATN + k4 * 4];
            acc[j] += xv.x * wr[0] + xv.y * wr[1] + xv.z * wr[2] + xv.w * wr[3];
        }
    }

    // heads
    float r0 = sigmoidf_(acc[0] + b_shs[0]);
    float r1 = sigmoidf_(acc[1] + b_shs[1]);
    float r2 = sigmoidf_(acc[2] + b_shs[2]);
    float s0 = fminf(expf(acc[3] + b_scale[0]), 0.2f);
    float s1 = fminf(expf(acc[4] + b_scale[1]), 0.2f);
    float s2 = fminf(expf(acc[5] + b_scale[2]), 0.2f);
    float o0 = (sigmoidf_(acc[6] + b_xyz[0]) - 0.5f) * 0.05f;
    float o1 = (sigmoidf_(acc[7] + b_xyz[1]) - 0.5f) * 0.05f;
    float o2 = (sigmoidf_(acc[8] + b_xyz[2]) - 0.5f) * 0.05f;
    float opac = sigmoidf_(acc[9] + b_opac[0]);
    float qw = acc[10] + b_rot[0];
    float qx = acc[11] + b_rot[1];
    float qy = acc[12] + b_rot[2];
    float qz = acc[13] + b_rot[3];
    float qn = sqrtf(qw * qw + qx * qx + qy * qy + qz * qz);
    qw /= qn; qx /= qn; qy /= qn; qz /= qn;

    float R[3][3];
    R[0][0] = 1.f - 2.f * (qy * qy + qz * qz);
    R[0][1] = 2.f * (qx * qy - qw * qz);
    R[0][2] = 2.f * (qx * qz + qw * qy);
    R[1][0] = 2.f * (qx * qy + qw * qz);
    R[1][1] = 1.f - 2.f * (qx * qx + qz * qz);
    R[1][2] = 2.f * (qy * qz - qw * qx);
    R[2][0] = 2.f * (qx * qz - qw * qy);
    R[2][1] = 2.f * (qy * qz + qw * qx);
    R[2][2] = 1.f - 2.f * (qx * qx + qy * qy);

    float sq[3] = { s0 * s0, s1 * s1, s2 * s2 };
    float cov[3][3];
#pragma unroll
    for (int i = 0; i < 3; i++)
#pragma unroll
        for (int k = 0; k < 3; k++)
            cov[i][k] = R[i][0] * sq[0] * R[k][0] + R[i][1] * sq[1] * R[k][1] + R[i][2] * sq[2] * R[k][2];

    float Rv[3][3], tv[3];
#pragma unroll
    for (int i = 0; i < 3; i++) {
#pragma unroll
        for (int j = 0; j < 3; j++) Rv[i][j] = vm[i * 4 + j];
        tv[i] = vm[i * 4 + 3];
    }
    float X0 = pts[g * 3 + 0] + o0;
    float X1 = pts[g * 3 + 1] + o1;
    float X2 = pts[g * 3 + 2] + o2;
    float p0 = Rv[0][0] * X0 + Rv[0][1] * X1 + Rv[0][2] * X2 + tv[0];
    float p1 = Rv[1][0] * X0 + Rv[1][1] * X1 + Rv[1][2] * X2 + tv[1];
    float p2 = Rv[2][0] * X0 + Rv[2][1] * X1 + Rv[2][2] * X2 + tv[2];
    float tz = fmaxf(p2, 0.001f);
    float u = 128.0f * p0 / tz + 64.0f;
    float v = 128.0f * p1 / tz + 64.0f;

    float j00 = 128.0f / tz, j02 = -128.0f * p0 / (tz * tz);
    float j11 = 128.0f / tz, j12 = -128.0f * p1 / (tz * tz);
    float M0[3], M1[3];
#pragma unroll
    for (int k = 0; k < 3; k++) {
        M0[k] = j00 * Rv[0][k] + j02 * Rv[2][k];
        M1[k] = j11 * Rv[1][k] + j12 * Rv[2][k];
    }
    float t0[3], t1[3];
#pragma unroll
    for (int k = 0; k < 3; k++) {
        t0[k] = M0[0] * cov[0][k] + M0[1] * cov[1][k] + M0[2] * cov[2][k];
        t1[k] = M1[0] * cov[0][k] + M1[1] * cov[1][k] + M1[2] * cov[2][k];
    }
    float A = t0[0] * M0[0] + t0[1] * M0[1] + t0[2] * M0[2] + 0.3f;
    float B = t0[0] * M1[0] + t0[1] * M1[1] + t0[2] * M1[2];
    float C = t1[0] * M1[0] + t1[1] * M1[1] + t1[2] * M1[2] + 0.3f;
    float det = A * C - B * B + 1e-12f;
    float cA = C / det, cB = -B / det, cC = A / det;

    if (p2 <= 0.01f) opac = 0.0f;   // vis mask folded into opacity

    ws[RAW_OFF + 0 * NG + g] = u;
    ws[RAW_OFF + 1 * NG + g] = v;
    ws[RAW_OFF + 2 * NG + g] = cA;
    ws[RAW_OFF + 3 * NG + g] = cB;
    ws[RAW_OFF + 4 * NG + g] = cC;
    ws[RAW_OFF + 5 * NG + g] = opac;
    ws[RAW_OFF + 6 * NG + g] = r0;
    ws[RAW_OFF + 7 * NG + g] = r1;
    ws[RAW_OFF + 8 * NG + g] = r2;
    ws[RAW_OFF + 9 * NG + g] = tz;
}

__global__ __launch_bounds__(1024) void k_sort(float* ws)
{
    __shared__ float key[NG];
    __shared__ int sidx[NG];
    int tid = threadIdx.x;
    const float* tz = ws + RAW_OFF + 9 * NG;
    for (int i = tid; i < NG; i += 1024) { key[i] = tz[i]; sidx[i] = i; }
    __syncthreads();
    for (int k = 2; k <= NG; k <<= 1) {
        for (int j = k >> 1; j > 0; j >>= 1) {
            for (int i = tid; i < NG; i += 1024) {
                int ixj = i ^ j;
                if (ixj > i) {
                    float ka = key[i], kb = key[ixj];
                    int ia = sidx[i], ib = sidx[ixj];
                    bool agtb = (ka > kb) || (ka == kb && ia > ib);
                    bool up = ((i & k) == 0);
                    if (up == agtb) {
                        key[i] = kb; key[ixj] = ka;
                        sidx[i] = ib; sidx[ixj] = ia;
                    }
                }
            }
            __syncthreads();
        }
    }
    // gather sorted params
    for (int s = tid; s < NG; s += 1024) {
        int g = sidx[s];
#pragma unroll
        for (int a = 0; a < 9; a++)
            ws[SORT_OFF + a * NG + s] = ws[RAW_OFF + a * NG + g];
    }
}

__global__ __launch_bounds__(256) void k_render(float* ws)
{
    __shared__ float s_u[CHSZ], s_v[CHSZ], s_ca[CHSZ], s_cb[CHSZ], s_cc[CHSZ];
    __shared__ float s_op[CHSZ], s_r[CHSZ], s_g[CHSZ], s_b[CHSZ];
    int tid = threadIdx.x;
    int p = blockIdx.x * 256 + tid;
    int c = blockIdx.y;
    int base = c * CHSZ + tid;
    const float* S = ws + SORT_OFF;
    s_u[tid]  = S[0 * NG + base];
    s_v[tid]  = S[1 * NG + base];
    s_ca[tid] = S[2 * NG + base];
    s_cb[tid] = S[3 * NG + base];
    s_cc[tid] = S[4 * NG + base];
    s_op[tid] = S[5 * NG + base];
    s_r[tid]  = S[6 * NG + base];
    s_g[tid]  = S[7 * NG + base];
    s_b[tid]  = S[8 * NG + base];
    __syncthreads();

    float gx = (float)(p & 127) + 0.5f;
    float gy = (float)(p >> 7) + 0.5f;
    float T = 1.0f, oR = 0.0f, oG = 0.0f, oB = 0.0f;
    for (int i = 0; i < CHSZ; i++) {
        float dx = gx - s_u[i];
        float dy = gy - s_v[i];
        float pw = -0.5f * (s_ca[i] * dx * dx + s_cc[i] * dy * dy) - s_cb[i] * dx * dy;
        pw = fminf(pw, 0.0f);
        float al = fminf(0.99f, s_op[i] * __expf(pw));
        al = (al < (1.0f / 255.0f)) ? 0.0f : al;
        float w = al * T;
        oR += w * s_r[i];
        oG += w * s_g[i];
        oB += w * s_b[i];
        T *= 1.0f - al;
    }
    ws[CT_OFF + c * NPIX + p] = T;
    ws[CA_OFF + (c * 3 + 0) * NPIX + p] = oR;
    ws[CA_OFF + (c * 3 + 1) * NPIX + p] = oG;
    ws[CA_OFF + (c * 3 + 2) * NPIX + p] = oB;
}

__global__ __launch_bounds__(256) void k_combine(const float* ws, float* out)
{
    int p = blockIdx.x * 256 + threadIdx.x;
    float T = 1.0f, oR = 0.0f, oG = 0.0f, oB = 0.0f;
#pragma unroll
    for (int c = 0; c < NCHUNK; c++) {
        oR += T * ws[CA_OFF + (c * 3 + 0) * NPIX + p];
        oG += T * ws[CA_OFF + (c * 3 + 1) * NPIX + p];
        oB += T * ws[CA_OFF + (c * 3 + 2) * NPIX + p];
        T *= ws[CT_OFF + c * NPIX + p];
    }
    out[p * 3 + 0] = oR;
    out[p * 3 + 1] = oG;
    out[p * 3 + 2] = oB;
}

extern "C" void kernel_launch(void* const* d_in, const int* in_sizes, int n_in,
                              void* d_out, int out_size, void* d_ws, size_t ws_size,
                              hipStream_t stream)
{
    const float* x       = (const float*)d_in[0];
    const float* pts     = (const float*)d_in[1];
    const float* viewmat = (const float*)d_in[2];
    const float* w_shs   = (const float*)d_in[3];
    const float* b_shs   = (const float*)d_in[4];
    const float* w_scale = (const float*)d_in[5];
    const float* b_scale = (const float*)d_in[6];
    const float* w_xyz   = (const float*)d_in[7];
    const float* b_xyz   = (const float*)d_in[8];
    const float* w_opac  = (const float*)d_in[9];
    const float* b_opac  = (const float*)d_in[10];
    const float* w_rot   = (const float*)d_in[11];
    const float* b_rot   = (const float*)d_in[12];
    float* ws = (float*)d_ws;
    float* out = (float*)d_out;

    k_pre<<<NG / 256, 256, 0, stream>>>(x, pts, viewmat, w_shs, b_shs, w_scale, b_scale,
                                        w_xyz, b_xyz, w_opac, b_opac, w_rot, b_rot, ws);
    k_sort<<<1, 1024, 0, stream>>>(ws);
    k_render<<<dim3(NPIX / 256, NCHUNK), 256, 0, stream>>>(ws);
    k_combine<<<NPIX / 256, 256, 0, stream>>>(ws, out);
}

// Round 2
// 61.631 us; speedup vs baseline: 1.4512x; 1.4512x over previous
//
#include <hip/hip_runtime.h>
#include <math.h>

#define NG 2048
#define FEATN 128
#define NPIX 16384
#define NCHUNK 8
#define CHSZ 256
#define LOG2E 1.4426950408889634f

// ws float-offsets
#define P_U   (0 * NG)
#define P_V   (1 * NG)
#define P_A   (2 * NG)   // -0.5*log2e*cA
#define P_B   (3 * NG)   // -log2e*cB
#define P_C   (4 * NG)   // -0.5*log2e*cC
#define P_OP  (5 * NG)
#define P_R   (6 * NG)
#define P_G   (7 * NG)
#define P_BL  (8 * NG)
#define P_RX  (9 * NG)
#define P_RY  (10 * NG)
#define KEY_OFF (12 * NG)   // u64[NG]
#define INV_OFF (16 * NG)   // int[NG]
#define CT_OFF  (20 * NG)   // float[NCHUNK*NPIX]
#define CA_OFF  (CT_OFF + NCHUNK * NPIX)

__device__ __forceinline__ float sigmoidf_(float z) { return 1.0f / (1.0f + expf(-z)); }

__global__ __launch_bounds__(64) void k_pre(
    const float* __restrict__ x, const float* __restrict__ pts, const float* __restrict__ vm,
    const float* __restrict__ w_shs, const float* __restrict__ b_shs,
    const float* __restrict__ w_scale, const float* __restrict__ b_scale,
    const float* __restrict__ w_xyz, const float* __restrict__ b_xyz,
    const float* __restrict__ w_opac, const float* __restrict__ b_opac,
    const float* __restrict__ w_rot, const float* __restrict__ b_rot,
    float* __restrict__ ws)
{
    __shared__ float sw[14 * FEATN];
    int tid = threadIdx.x;
    for (int i = tid; i < 14 * FEATN; i += 64) {
        int r = i >> 7, c0 = i & 127;
        float v;
        if (r < 3)       v = w_shs[r * FEATN + c0];
        else if (r < 6)  v = w_scale[(r - 3) * FEATN + c0];
        else if (r < 9)  v = w_xyz[(r - 6) * FEATN + c0];
        else if (r == 9) v = w_opac[c0];
        else             v = w_rot[(r - 10) * FEATN + c0];
        sw[i] = v;
    }
    __syncthreads();
    int g = blockIdx.x * 64 + tid;

    float acc[14];
#pragma unroll
    for (int j = 0; j < 14; j++) acc[j] = 0.0f;
    const float4* x4 = (const float4*)(x + (size_t)g * FEATN);
#pragma unroll 4
    for (int k4 = 0; k4 < FEATN / 4; k4++) {
        float4 xv = x4[k4];
#pragma unroll
        for (int j = 0; j < 14; j++) {
            const float* wr = &sw[j * FEATN + k4 * 4];
            acc[j] += xv.x * wr[0] + xv.y * wr[1] + xv.z * wr[2] + xv.w * wr[3];
        }
    }

    float r0 = sigmoidf_(acc[0] + b_shs[0]);
    float r1 = sigmoidf_(acc[1] + b_shs[1]);
    float r2 = sigmoidf_(acc[2] + b_shs[2]);
    float s0 = fminf(expf(acc[3] + b_scale[0]), 0.2f);
    float s1 = fminf(expf(acc[4] + b_scale[1]), 0.2f);
    float s2 = fminf(expf(acc[5] + b_scale[2]), 0.2f);
    float o0 = (sigmoidf_(acc[6] + b_xyz[0]) - 0.5f) * 0.05f;
    float o1 = (sigmoidf_(acc[7] + b_xyz[1]) - 0.5f) * 0.05f;
    float o2 = (sigmoidf_(acc[8] + b_xyz[2]) - 0.5f) * 0.05f;
    float opac = sigmoidf_(acc[9] + b_opac[0]);
    float qw = acc[10] + b_rot[0];
    float qx = acc[11] + b_rot[1];
    float qy = acc[12] + b_rot[2];
    float qz = acc[13] + b_rot[3];
    float qn = sqrtf(qw * qw + qx * qx + qy * qy + qz * qz);
    qw /= qn; qx /= qn; qy /= qn; qz /= qn;

    float R[3][3];
    R[0][0] = 1.f - 2.f * (qy * qy + qz * qz);
    R[0][1] = 2.f * (qx * qy - qw * qz);
    R[0][2] = 2.f * (qx * qz + qw * qy);
    R[1][0] = 2.f * (qx * qy + qw * qz);
    R[1][1] = 1.f - 2.f * (qx * qx + qz * qz);
    R[1][2] = 2.f * (qy * qz - qw * qx);
    R[2][0] = 2.f * (qx * qz - qw * qy);
    R[2][1] = 2.f * (qy * qz + qw * qx);
    R[2][2] = 1.f - 2.f * (qx * qx + qy * qy);

    float sq[3] = { s0 * s0, s1 * s1, s2 * s2 };
    float cov[3][3];
#pragma unroll
    for (int i = 0; i < 3; i++)
#pragma unroll
        for (int k = 0; k < 3; k++)
            cov[i][k] = R[i][0] * sq[0] * R[k][0] + R[i][1] * sq[1] * R[k][1] + R[i][2] * sq[2] * R[k][2];

    float Rv[3][3], tv[3];
#pragma unroll
    for (int i = 0; i < 3; i++) {
#pragma unroll
        for (int j = 0; j < 3; j++) Rv[i][j] = vm[i * 4 + j];
        tv[i] = vm[i * 4 + 3];
    }
    float X0 = pts[g * 3 + 0] + o0;
    float X1 = pts[g * 3 + 1] + o1;
    float X2 = pts[g * 3 + 2] + o2;
    float p0 = Rv[0][0] * X0 + Rv[0][1] * X1 + Rv[0][2] * X2 + tv[0];
    float p1 = Rv[1][0] * X0 + Rv[1][1] * X1 + Rv[1][2] * X2 + tv[1];
    float p2 = Rv[2][0] * X0 + Rv[2][1] * X1 + Rv[2][2] * X2 + tv[2];
    float tz = fmaxf(p2, 0.001f);
    float u = 128.0f * p0 / tz + 64.0f;
    float v = 128.0f * p1 / tz + 64.0f;

    float j00 = 128.0f / tz, j02 = -128.0f * p0 / (tz * tz);
    float j11 = 128.0f / tz, j12 = -128.0f * p1 / (tz * tz);
    float M0[3], M1[3];
#pragma unroll
    for (int k = 0; k < 3; k++) {
        M0[k] = j00 * Rv[0][k] + j02 * Rv[2][k];
        M1[k] = j11 * Rv[1][k] + j12 * Rv[2][k];
    }
    float t0[3], t1[3];
#pragma unroll
    for (int k = 0; k < 3; k++) {
        t0[k] = M0[0] * cov[0][k] + M0[1] * cov[1][k] + M0[2] * cov[2][k];
        t1[k] = M1[0] * cov[0][k] + M1[1] * cov[1][k] + M1[2] * cov[2][k];
    }
    float A = t0[0] * M0[0] + t0[1] * M0[1] + t0[2] * M0[2] + 0.3f;
    float B = t0[0] * M1[0] + t0[1] * M1[1] + t0[2] * M1[2];
    float C = t1[0] * M1[0] + t1[1] * M1[1] + t1[2] * M1[2] + 0.3f;
    float det = A * C - B * B + 1e-12f;
    float cA = C / det, cB = -B / det, cC = A / det;

    if (p2 <= 0.01f) opac = 0.0f;   // vis mask folded into opacity

    // conservative per-gaussian bounding half-extents (alpha >= 1/255 region)
    float rx, ry;
    if (opac >= 1.0f / 255.0f) {
        float L = 2.0f * logf(255.0f * opac);
        rx = sqrtf(L * A) + 0.5f;
        ry = sqrtf(L * C) + 0.5f;
    } else {
        rx = -1e9f; ry = -1e9f;   // never kept
    }

    ws[P_U + g]  = u;
    ws[P_V + g]  = v;
    ws[P_A + g]  = -0.5f * LOG2E * cA;
    ws[P_B + g]  = -LOG2E * cB;
    ws[P_C + g]  = -0.5f * LOG2E * cC;
    ws[P_OP + g] = opac;
    ws[P_R + g]  = r0;
    ws[P_G + g]  = r1;
    ws[P_BL + g] = r2;
    ws[P_RX + g] = rx;
    ws[P_RY + g] = ry;

    unsigned kb = __float_as_uint(tz);   // tz > 0 -> bits monotone in value
    ((unsigned long long*)(ws + KEY_OFF))[g] =
        ((unsigned long long)kb << 32) | (unsigned)g;
}

__global__ __launch_bounds__(64) void k_rank(float* __restrict__ ws)
{
    __shared__ unsigned long long sk[NG];
    const unsigned long long* __restrict__ key = (const unsigned long long*)(ws + KEY_OFF);
    int tid = threadIdx.x;
    for (int i = tid; i < NG; i += 64) sk[i] = key[i];
    __syncthreads();
    int g = blockIdx.x * 64 + tid;
    unsigned long long mk = sk[g];
    int rank = 0;
    for (int j = 0; j < NG; j += 8) {
        int r0 = (sk[j + 0] < mk) ? 1 : 0;
        int r1 = (sk[j + 1] < mk) ? 1 : 0;
        int r2 = (sk[j + 2] < mk) ? 1 : 0;
        int r3 = (sk[j + 3] < mk) ? 1 : 0;
        int r4 = (sk[j + 4] < mk) ? 1 : 0;
        int r5 = (sk[j + 5] < mk) ? 1 : 0;
        int r6 = (sk[j + 6] < mk) ? 1 : 0;
        int r7 = (sk[j + 7] < mk) ? 1 : 0;
        rank += ((r0 + r1) + (r2 + r3)) + ((r4 + r5) + (r6 + r7));
    }
    ((int*)(ws + INV_OFF))[rank] = g;
}

__global__ __launch_bounds__(256) void k_render(float* __restrict__ ws)
{
    __shared__ float sg[CHSZ * 12];
    __shared__ int s_cnt[4];
    int tid = threadIdx.x;
    int tile = blockIdx.x, c = blockIdx.y;
    int tx0 = (tile & 7) << 4, ty0 = (tile >> 3) << 4;
    int s = c * CHSZ + tid;
    int g = ((const int*)(ws + INV_OFF))[s];

    float u  = ws[P_U + g],  v  = ws[P_V + g];
    float rx = ws[P_RX + g], ry = ws[P_RY + g];
    float x0 = tx0 + 0.5f, x1 = tx0 + 15.5f;
    float y0 = ty0 + 0.5f, y1 = ty0 + 15.5f;
    bool keep = (u + rx >= x0) && (u - rx <= x1) && (v + ry >= y0) && (v - ry <= y1);

    unsigned long long mask = __ballot(keep);
    int wid = tid >> 6, lane = tid & 63;
    if (lane == 0) s_cnt[wid] = __popcll(mask);
    __syncthreads();
    int base = 0;
#pragma unroll
    for (int w2 = 0; w2 < 4; w2++) if (w2 < wid) base += s_cnt[w2];
    int n = s_cnt[0] + s_cnt[1] + s_cnt[2] + s_cnt[3];
    if (keep) {
        int pos = base + __popcll(mask & ((1ull << lane) - 1ull));
        float* d = &sg[pos * 12];
        d[0] = u;             d[1] = v;
        d[2] = ws[P_A + g];   d[3] = ws[P_B + g];
        d[4] = ws[P_C + g];   d[5] = ws[P_OP + g];
        d[6] = ws[P_R + g];   d[7] = ws[P_G + g];
        d[8] = ws[P_BL + g];
    }
    __syncthreads();

    float gx = x0 + (float)(tid & 15);
    float gy = y0 + (float)(tid >> 4);
    float T = 1.0f, oR = 0.0f, oG = 0.0f, oB = 0.0f;
    for (int i = 0; i < n; i++) {
        const float* d = &sg[i * 12];
        float4 q0 = *(const float4*)d;        // u,v,a2,b2
        float4 q1 = *(const float4*)(d + 4);  // c2,op,r,g
        float bb = d[8];
        float dx = gx - q0.x;
        float dy = gy - q0.y;
        float pw = dx * (q0.z * dx + q0.w * dy) + q1.x * dy * dy;  // log2-scaled power
        pw = fminf(pw, 0.0f);
        float al = fminf(0.99f, q1.y * exp2f(pw));
        al = (al < 1.0f / 255.0f) ? 0.0f : al;
        float w = al * T;
        oR += w * q1.z;
        oG += w * q1.w;
        oB += w * bb;
        T -= al * T;
    }
    int p = (ty0 + (tid >> 4)) * 128 + tx0 + (tid & 15);
    ws[CT_OFF + c * NPIX + p] = T;
    ws[CA_OFF + (3 * c + 0) * NPIX + p] = oR;
    ws[CA_OFF + (3 * c + 1) * NPIX + p] = oG;
    ws[CA_OFF + (3 * c + 2) * NPIX + p] = oB;
}

__global__ __launch_bounds__(256) void k_combine(const float* __restrict__ ws, float* __restrict__ out)
{
    int p = blockIdx.x * 256 + threadIdx.x;
    float T = 1.0f, oR = 0.0f, oG = 0.0f, oB = 0.0f;
#pragma unroll
    for (int c = 0; c < NCHUNK; c++) {
        float t = ws[CT_OFF + c * NPIX + p];
        oR += T * ws[CA_OFF + (3 * c + 0) * NPIX + p];
        oG += T * ws[CA_OFF + (3 * c + 1) * NPIX + p];
        oB += T * ws[CA_OFF + (3 * c + 2) * NPIX + p];
        T *= t;
    }
    out[p * 3 + 0] = oR;
    out[p * 3 + 1] = oG;
    out[p * 3 + 2] = oB;
}

extern "C" void kernel_launch(void* const* d_in, const int* in_sizes, int n_in,
                              void* d_out, int out_size, void* d_ws, size_t ws_size,
                              hipStream_t stream)
{
    const float* x       = (const float*)d_in[0];
    const float* pts     = (const float*)d_in[1];
    const float* viewmat = (const float*)d_in[2];
    const float* w_shs   = (const float*)d_in[3];
    const float* b_shs   = (const float*)d_in[4];
    const float* w_scale = (const float*)d_in[5];
    const float* b_scale = (const float*)d_in[6];
    const float* w_xyz   = (const float*)d_in[7];
    const float* b_xyz   = (const float*)d_in[8];
    const float* w_opac  = (const float*)d_in[9];
    const float* b_opac  = (const float*)d_in[10];
    const float* w_rot   = (const float*)d_in[11];
    const float* b_rot   = (const float*)d_in[12];
    float* ws = (float*)d_ws;
    float* out = (float*)d_out;

    k_pre<<<NG / 64, 64, 0, stream>>>(x, pts, viewmat, w_shs, b_shs, w_scale, b_scale,
                                      w_xyz, b_xyz, w_opac, b_opac, w_rot, b_rot, ws);
    k_rank<<<NG / 64, 64, 0, stream>>>(ws);
    k_render<<<dim3(64, NCHUNK), 256, 0, stream>>>(ws);
    k_combine<<<NPIX / 256, 256, 0, stream>>>(ws, out);
}